// Round 1
// baseline (1079.794 us; speedup 1.0000x reference)
//
#include <hip/hip_runtime.h>

#define BIMG 8
#define NBOX 100000
#define NCLS 80
#define KDET 300
#define CAP  2048
#define NB   32
#define PUSH_BIN 30          // bin >= 30  <=>  score >= 126/128 = 0.984375
#define SCORE_T 0.05f
#define WND  64

// workspace layout (bytes)
#define OFF_HIST    0u          // 640*32*4 = 81920
#define OFF_PUSHCNT 81920u      // 640*4
#define OFF_CUTBIN  84480u      // 640*4
#define OFF_FBFLAG  87040u      // 640*4
#define OFF_ANYFB   89600u      // 8*4
#define ZERO_BYTES  90112u
#define OFF_BUF     90112u      // 640*2048*8 = 10485760
#define OFF_KCNT    10575872u   // 640*4
#define OFF_KSC     10578432u   // 640*300*4
#define OFF_KIDX    11346432u   // 640*300*4

// ---------------- pass A: histogram + opportunistic push ----------------
__global__ __launch_bounds__(256) void histK(const float* __restrict__ cls,
                                             unsigned* __restrict__ hist,
                                             unsigned* __restrict__ pushcnt,
                                             unsigned long long* __restrict__ buf) {
  __shared__ unsigned h[NCLS * NB];   // 10 KB
  const int t = threadIdx.x;
  const int b = blockIdx.y;
  for (int i = t; i < NCLS * NB; i += 256) h[i] = 0;
  __syncthreads();

  const float4* base = (const float4*)(cls + (size_t)b * NBOX * NCLS);
  const int start = blockIdx.x * 16384;      // 256 threads * 64 iters
  for (int it = 0; it < 64; ++it) {
    int q = start + it * 256 + t;
    if (q >= 2000000) break;                 // N*C/4
    float4 v = base[q];
    int e0 = q * 4;
    int c0 = e0 % NCLS;
    float s4[4] = {v.x, v.y, v.z, v.w};
#pragma unroll
    for (int j = 0; j < 4; ++j) {
      float sc = s4[j];
      if (sc > 0.75f) {
        int bin = (int)(sc * 128.0f) - 96;
        if (bin > NB - 1) bin = NB - 1;
        atomicAdd(&h[(c0 + j) * NB + bin], 1u);
        if (bin >= PUSH_BIN && sc > SCORE_T) {
          int n = e0 / NCLS;
          int bc = b * NCLS + c0 + j;
          unsigned slot = atomicAdd(&pushcnt[bc], 1u);
          if (slot < CAP)
            buf[(size_t)bc * CAP + slot] =
                ((unsigned long long)__float_as_uint(sc) << 32) | (unsigned)(~(unsigned)n);
        }
      }
    }
  }
  __syncthreads();
  for (int i = t; i < NCLS * NB; i += 256) {
    unsigned v = h[i];
    if (v) atomicAdd(&hist[(size_t)b * NCLS * NB + i], v);
  }
}

// ---------------- pass A2: cutoff + fallback decision ----------------
__global__ void cutK(const unsigned* __restrict__ hist, unsigned* __restrict__ pushcnt,
                     int* __restrict__ cutbin, unsigned* __restrict__ fbflag,
                     unsigned* __restrict__ anyfb) {
  int t = threadIdx.x;   // 0..639 == bc
  const unsigned* hh = hist + (size_t)t * NB;
  int acc = 0, bstar = -1;
  for (int bn = NB - 1; bn >= 0; --bn) {
    acc += hh[bn];
    if (acc >= KDET) { bstar = bn; break; }
  }
  cutbin[t] = bstar;
  unsigned cnt = pushcnt[t];
  int fb = (bstar < PUSH_BIN) || (cnt > CAP);
  fbflag[t] = fb ? 1u : 0u;
  if (fb) { pushcnt[t] = 0; atomicOr(&anyfb[t / NCLS], 1u); }
}

// ---------------- pass B: exact fallback re-push (early-exits) ----------------
__global__ __launch_bounds__(256) void fbK(const float* __restrict__ cls,
                                           const int* __restrict__ cutbin,
                                           const unsigned* __restrict__ fbflag,
                                           const unsigned* __restrict__ anyfb,
                                           unsigned* __restrict__ pushcnt,
                                           unsigned long long* __restrict__ buf) {
  const int b = blockIdx.y;
  if (anyfb[b] == 0) return;
  const int t = threadIdx.x;
  const float4* base = (const float4*)(cls + (size_t)b * NBOX * NCLS);
  const int start = blockIdx.x * 16384;
  for (int it = 0; it < 64; ++it) {
    int q = start + it * 256 + t;
    if (q >= 2000000) break;
    float4 v = base[q];
    int e0 = q * 4;
    int c0 = e0 % NCLS;
    int n = e0 / NCLS;
    float s4[4] = {v.x, v.y, v.z, v.w};
#pragma unroll
    for (int j = 0; j < 4; ++j) {
      int bc = b * NCLS + c0 + j;
      if (!fbflag[bc]) continue;
      float sc = s4[j];
      if (!(sc > SCORE_T)) continue;
      int bs = cutbin[bc];
      bool take;
      if (bs < 0) take = true;
      else if (sc > 0.75f) {
        int bin = (int)(sc * 128.0f) - 96;
        if (bin > NB - 1) bin = NB - 1;
        take = (bin >= bs);
      } else take = false;
      if (take) {
        unsigned slot = atomicAdd(&pushcnt[bc], 1u);
        if (slot < CAP)
          buf[(size_t)bc * CAP + slot] =
              ((unsigned long long)__float_as_uint(sc) << 32) | (unsigned)(~(unsigned)n);
      }
    }
  }
}

// ---------------- per (b,c): exact sort + NMS + compact kept ----------------
__global__ __launch_bounds__(256) void nmsK(const float* __restrict__ boxes,
                                            const unsigned* __restrict__ pushcnt,
                                            const unsigned long long* __restrict__ buf,
                                            unsigned* __restrict__ keptCnt,
                                            float* __restrict__ keptScore,
                                            unsigned* __restrict__ keptIdx) {
  __shared__ unsigned long long sb[CAP];        // 16 KB
  __shared__ float bx[KDET][4];                 // 4.8 KB
  __shared__ float scl[KDET];
  __shared__ unsigned nn[KDET];
  __shared__ unsigned long long msk[KDET][5];   // 12 KB
  __shared__ unsigned long long anyw[5];
  __shared__ unsigned long long keptw[5];

  const int t = threadIdx.x;
  const int bc = blockIdx.x;
  const int b = bc / NCLS;
  const int cnt = min((int)pushcnt[bc], CAP);
  const unsigned long long* src = buf + (size_t)bc * CAP;
  for (int i = t; i < CAP; i += 256) sb[i] = (i < cnt) ? src[i] : 0ull;
  if (t < 5) anyw[t] = 0ull;
  __syncthreads();

  // bitonic sort descending (2048-key network, u64 keys = (score_bits, ~n))
  for (int k = 2; k <= CAP; k <<= 1) {
    for (int j = k >> 1; j > 0; j >>= 1) {
      for (int i = t; i < CAP; i += 256) {
        int ixj = i ^ j;
        if (ixj > i) {
          unsigned long long a = sb[i], c2 = sb[ixj];
          bool up = ((i & k) == 0);
          if (up ? (a < c2) : (a > c2)) { sb[i] = c2; sb[ixj] = a; }
        }
      }
      __syncthreads();
    }
  }

  const int M = min(cnt, KDET);
  for (int i = t; i < M; i += 256) {
    unsigned long long key = sb[i];
    unsigned n = ~(unsigned)(key & 0xFFFFFFFFull);
    scl[i] = __uint_as_float((unsigned)(key >> 32));
    nn[i] = n;
    const float4 bv = *(const float4*)(boxes + ((size_t)b * NBOX + n) * 4);
    bx[i][0] = bv.x; bx[i][1] = bv.y; bx[i][2] = bv.z; bx[i][3] = bv.w;
  }
  __syncthreads();

  // suppression masks: bit j set in msk[i] iff IoU(box_i, box_j) >= 0.5, j < i
  for (int i = t; i < M; i += 256) {
    float x1 = bx[i][0], y1 = bx[i][1], x2 = bx[i][2], y2 = bx[i][3];
    float a1 = (x2 - x1) * (y2 - y1);
    unsigned long long m0 = 0, m1 = 0, m2 = 0, m3 = 0, m4 = 0;
    for (int j = 0; j < i; ++j) {
      float lx = fmaxf(x1, bx[j][0]);
      float ly = fmaxf(y1, bx[j][1]);
      float rx = fminf(x2, bx[j][2]);
      float ry = fminf(y2, bx[j][3]);
      float iw = fmaxf(rx - lx, 0.0f), ih = fmaxf(ry - ly, 0.0f);
      float inter = iw * ih;
      float a2 = (bx[j][2] - bx[j][0]) * (bx[j][3] - bx[j][1]);
      float uni = fmaxf(a1 + a2 - inter, 1e-7f);
      float iou = inter / uni;   // true division to match reference rounding
      if (iou >= 0.5f) {
        unsigned long long bit = 1ull << (j & 63);
        switch (j >> 6) {
          case 0: m0 |= bit; break;
          case 1: m1 |= bit; break;
          case 2: m2 |= bit; break;
          case 3: m3 |= bit; break;
          default: m4 |= bit; break;
        }
      }
    }
    msk[i][0] = m0; msk[i][1] = m1; msk[i][2] = m2; msk[i][3] = m3; msk[i][4] = m4;
    if (m0 | m1 | m2 | m3 | m4) atomicOr(&anyw[i >> 6], 1ull << (i & 63));
  }
  __syncthreads();

  if (t == 0) {
    unsigned long long kw[5] = {0, 0, 0, 0, 0};
    unsigned long long aw[5] = {anyw[0], anyw[1], anyw[2], anyw[3], anyw[4]};
    for (int i = 0; i < M; ++i) {
      bool sup = false;
      if ((aw[i >> 6] >> (i & 63)) & 1ull) {
        unsigned long long s0 = (msk[i][0] & kw[0]) | (msk[i][1] & kw[1]) |
                                (msk[i][2] & kw[2]) | (msk[i][3] & kw[3]) |
                                (msk[i][4] & kw[4]);
        sup = (s0 != 0ull);
      }
      if (!sup) kw[i >> 6] |= 1ull << (i & 63);
    }
    keptw[0] = kw[0]; keptw[1] = kw[1]; keptw[2] = kw[2]; keptw[3] = kw[3]; keptw[4] = kw[4];
  }
  __syncthreads();

  for (int i = t; i < M; i += 256) {
    if ((keptw[i >> 6] >> (i & 63)) & 1ull) {
      int rank = 0;
      for (int w = 0; w < (i >> 6); ++w) rank += __popcll(keptw[w]);
      rank += __popcll(keptw[i >> 6] & ((1ull << (i & 63)) - 1ull));
      keptScore[(size_t)bc * KDET + rank] = scl[i];
      keptIdx[(size_t)bc * KDET + rank] = nn[i];
    }
  }
  if (t == 0) {
    int tot = 0;
    for (int w = 0; w < 5; ++w) tot += __popcll(keptw[w]);
    keptCnt[bc] = (unsigned)tot;
  }
}

// ---------------- per image: 80-way merge of sorted kept lists ----------------
__global__ __launch_bounds__(64) void mergeK(const float* __restrict__ boxes,
                                             const unsigned* __restrict__ keptCnt,
                                             const float* __restrict__ keptScore,
                                             const unsigned* __restrict__ keptIdx,
                                             float* __restrict__ out) {
  __shared__ float win[NCLS][WND + 1];     // +1 pad: banks spread
  __shared__ int scnt[NCLS];
  __shared__ unsigned long long wkey[KDET];
  __shared__ int wptr[KDET];

  const int lane = threadIdx.x;
  const int b = blockIdx.x;

  for (int c = lane; c < NCLS; c += 64) scnt[c] = min((int)keptCnt[b * NCLS + c], KDET);
  __syncthreads();
  for (int idx = lane; idx < NCLS * WND; idx += 64) {
    int c = idx >> 6, i = idx & 63;
    if (i < scnt[c]) win[c][i] = keptScore[((size_t)b * NCLS + c) * KDET + i];
  }
  __syncthreads();

  const int cnt0 = scnt[lane];
  const int cnt1 = (lane < 16) ? scnt[64 + lane] : 0;
  int p0 = 0, p1 = 0;

  for (int step = 0; step < KDET; ++step) {
    unsigned long long k0 = 0, k1 = 0;
    if (p0 < cnt0) {
      float s = (p0 < WND) ? win[lane][p0]
                           : keptScore[((size_t)b * NCLS + lane) * KDET + p0];
      k0 = ((unsigned long long)__float_as_uint(s) << 32) | (unsigned)(~(unsigned)lane);
    }
    if (lane < 16 && p1 < cnt1) {
      int c = 64 + lane;
      float s = (p1 < WND) ? win[c][p1]
                           : keptScore[((size_t)b * NCLS + c) * KDET + p1];
      k1 = ((unsigned long long)__float_as_uint(s) << 32) | (unsigned)(~(unsigned)c);
    }
    unsigned long long key = (k0 > k1) ? k0 : k1;
#pragma unroll
    for (int off = 32; off > 0; off >>= 1) {
      unsigned long long o = __shfl_xor(key, off);
      if (o > key) key = o;
    }
    if (key == 0ull) {
      if (lane == 0) wkey[step] = 0ull;
    } else {
      unsigned c = ~(unsigned)(key & 0xFFFFFFFFull);
      int wl = (int)(c & 63);
      if (lane == wl) {
        if ((int)c == lane) { wptr[step] = p0; ++p0; }
        else               { wptr[step] = p1; ++p1; }
        wkey[step] = key;
      }
    }
  }
  __syncthreads();

  // outputs: boxes [B,K,4] | scores [B,K] | labels [B,K] (as float)
  float* ob_base = out;
  float* os_base = out + (size_t)BIMG * KDET * 4;
  float* ol_base = out + (size_t)BIMG * KDET * 4 + (size_t)BIMG * KDET;
  for (int w = lane; w < KDET; w += 64) {
    unsigned long long key = wkey[w];
    float* ob = ob_base + ((size_t)b * KDET + w) * 4;
    if (key == 0ull) {
      *(float4*)ob = make_float4(-1.f, -1.f, -1.f, -1.f);
      os_base[(size_t)b * KDET + w] = -1.f;
      ol_base[(size_t)b * KDET + w] = -1.f;
    } else {
      unsigned c = ~(unsigned)(key & 0xFFFFFFFFull);
      float sc = __uint_as_float((unsigned)(key >> 32));
      unsigned n = keptIdx[((size_t)b * NCLS + c) * KDET + wptr[w]];
      *(float4*)ob = *(const float4*)(boxes + ((size_t)b * NBOX + n) * 4);
      os_base[(size_t)b * KDET + w] = sc;
      ol_base[(size_t)b * KDET + w] = (float)c;
    }
  }
}

extern "C" void kernel_launch(void* const* d_in, const int* in_sizes, int n_in,
                              void* d_out, int out_size, void* d_ws, size_t ws_size,
                              hipStream_t stream) {
  const float* boxes = (const float*)d_in[0];
  const float* cls = (const float*)d_in[1];
  float* out = (float*)d_out;
  char* ws = (char*)d_ws;

  unsigned* hist = (unsigned*)(ws + OFF_HIST);
  unsigned* pushcnt = (unsigned*)(ws + OFF_PUSHCNT);
  int* cutbin = (int*)(ws + OFF_CUTBIN);
  unsigned* fbflag = (unsigned*)(ws + OFF_FBFLAG);
  unsigned* anyfb = (unsigned*)(ws + OFF_ANYFB);
  unsigned long long* buf = (unsigned long long*)(ws + OFF_BUF);
  unsigned* keptCnt = (unsigned*)(ws + OFF_KCNT);
  float* keptScore = (float*)(ws + OFF_KSC);
  unsigned* keptIdx = (unsigned*)(ws + OFF_KIDX);

  hipMemsetAsync(ws, 0, ZERO_BYTES, stream);

  dim3 gridA(123, BIMG);   // 123*16384 >= 2,000,000 float4 per image
  histK<<<gridA, 256, 0, stream>>>(cls, hist, pushcnt, buf);
  cutK<<<1, BIMG * NCLS, 0, stream>>>(hist, pushcnt, cutbin, fbflag, anyfb);
  fbK<<<gridA, 256, 0, stream>>>(cls, cutbin, fbflag, anyfb, pushcnt, buf);
  nmsK<<<BIMG * NCLS, 256, 0, stream>>>(boxes, pushcnt, buf, keptCnt, keptScore, keptIdx);
  mergeK<<<BIMG, 64, 0, stream>>>(boxes, keptCnt, keptScore, keptIdx, out);
}

// Round 2
// 690.808 us; speedup vs baseline: 1.5631x; 1.5631x over previous
//
#include <hip/hip_runtime.h>

#define BIMG 8
#define NBOX 100000
#define NCLS 80
#define KDET 300
#define CAP  2048
#define CAPC 20                 // per-block per-class LDS staging capacity
#define TPUSH 0.984375f         // common-path push threshold
#define SCORE_T 0.05f
#define NELEM 8000000           // N*C per image
#define NQ    2000000           // float4s per image

// workspace layout (bytes)
#define OFF_PUSHCNT 0u              // 640*4 = 2560
#define ZERO_BYTES  2560u
#define OFF_BUF     4096u           // 640*2048*8 = 10485760
#define OFF_KCNT    (4096u + 10485760u)     // 640*4
#define OFF_KSC     (OFF_KCNT + 2560u)      // 640*300*4
#define OFF_KIDX    (OFF_KSC + 768000u)     // 640*300*4

static __device__ __forceinline__ unsigned long long mk_key(float sc, int n) {
  return ((unsigned long long)__float_as_uint(sc) << 32) | (unsigned)(~(unsigned)n);
}

// ---------------- pass A: threshold push with block-local aggregation ----------------
__global__ __launch_bounds__(256) void histK(const float* __restrict__ cls,
                                             unsigned* __restrict__ pushcnt,
                                             unsigned long long* __restrict__ buf) {
  __shared__ unsigned lcnt[NCLS];
  __shared__ unsigned sbase[NCLS];
  __shared__ unsigned long long stage[NCLS * CAPC];   // 12.8 KB

  const int t = threadIdx.x;
  const int b = blockIdx.y;
  for (int i = t; i < NCLS; i += 256) lcnt[i] = 0;
  __syncthreads();

  const float4* base = (const float4*)(cls + (size_t)b * NELEM);
  const int start = blockIdx.x * 8192;   // 246 blocks/img * 8192 float4 >= 2M

  for (int it = 0; it < 8; ++it) {
    const int q0 = start + it * 1024 + t;
    const int q1 = q0 + 256, q2 = q0 + 512, q3 = q0 + 768;
    // 4 independent loads in flight before any use
    float4 v0 = (q0 < NQ) ? base[q0] : make_float4(0.f, 0.f, 0.f, 0.f);
    float4 v1 = (q1 < NQ) ? base[q1] : make_float4(0.f, 0.f, 0.f, 0.f);
    float4 v2 = (q2 < NQ) ? base[q2] : make_float4(0.f, 0.f, 0.f, 0.f);
    float4 v3 = (q3 < NQ) ? base[q3] : make_float4(0.f, 0.f, 0.f, 0.f);

    const float4 vv[4] = {v0, v1, v2, v3};
    const int qq[4] = {q0, q1, q2, q3};
#pragma unroll
    for (int u = 0; u < 4; ++u) {
      const float4 v = vv[u];
      float mx = fmaxf(fmaxf(v.x, v.y), fmaxf(v.z, v.w));
      if (mx >= TPUSH) {
        const int e0 = qq[u] * 4;
        const int c0 = e0 % NCLS;       // float4-aligned: c0+j < NCLS always
        const int n = e0 / NCLS;
        const float s4[4] = {v.x, v.y, v.z, v.w};
#pragma unroll
        for (int j = 0; j < 4; ++j) {
          if (s4[j] >= TPUSH) {
            const int c = c0 + j;
            const unsigned long long key = mk_key(s4[j], n);
            unsigned slot = atomicAdd(&lcnt[c], 1u);
            if (slot < CAPC) {
              stage[c * CAPC + slot] = key;
            } else {   // rare LDS-staging overflow: direct global push
              unsigned g = atomicAdd(&pushcnt[b * NCLS + c], 1u);
              if (g < CAP) buf[(size_t)(b * NCLS + c) * CAP + g] = key;
            }
          }
        }
      }
    }
  }
  __syncthreads();

  // one global atomic per (block, class) to reserve a contiguous range
  if (t < NCLS) {
    unsigned cnt = min(lcnt[t], (unsigned)CAPC);
    sbase[t] = cnt ? atomicAdd(&pushcnt[b * NCLS + t], cnt) : 0u;
  }
  __syncthreads();
  for (int idx = t; idx < NCLS * CAPC; idx += 256) {
    const int c = idx / CAPC;
    const int k = idx - c * CAPC;
    if ((unsigned)k < min(lcnt[c], (unsigned)CAPC)) {
      unsigned s = sbase[c] + (unsigned)k;
      if (s < CAP) buf[(size_t)(b * NCLS + c) * CAP + s] = stage[idx];
    }
  }
}

// ---------------- fallback: exact radix-select re-push (early-exits; never runs on
// common inputs). One block per (b,c). ----------------
__global__ __launch_bounds__(256) void fbK(const float* __restrict__ cls,
                                           unsigned* __restrict__ pushcnt,
                                           unsigned long long* __restrict__ buf) {
  const int bc = blockIdx.x;
  const unsigned cnt = pushcnt[bc];
  if (cnt >= KDET && cnt <= CAP) return;   // common path: superset covers top-300

  __shared__ unsigned hist[2048];          // 8 KB
  __shared__ unsigned sprefix, sk, sabove, seq, stot, smode;

  const int t = threadIdx.x;
  const int b = bc / NCLS, c = bc % NCLS;
  const float* col = cls + (size_t)b * NELEM + c;
  if (t == 0) { atomicExch(&pushcnt[bc], 0u); smode = 0; }

  // MSD radix-select of the 300th-largest score-bits (positive floats: bits monotone)
  for (int r = 0; r < 3; ++r) {
    const int shift = (r == 0) ? 21 : (r == 1) ? 10 : 0;
    const int nbins = (r == 2) ? 1024 : 2048;
    for (int i = t; i < nbins; i += 256) hist[i] = 0;
    __syncthreads();
    for (int n = t; n < NBOX; n += 256) {
      float sc = col[(size_t)n * NCLS];
      if (sc > SCORE_T) {
        unsigned u = __float_as_uint(sc);
        bool ok = (r == 0) || (r == 1 ? ((u >> 21) == (sprefix >> 21))
                                      : ((u >> 10) == (sprefix >> 10)));
        if (ok) atomicAdd(&hist[(u >> shift) & (unsigned)(nbins - 1)], 1u);
      }
    }
    __syncthreads();
    if (t == 0) {
      if (r == 0) {
        unsigned s = 0;
        for (int i = 0; i < nbins; ++i) s += hist[i];
        stot = s;
        if (s < KDET) smode = 1;   // fewer than 300 candidates: push all
      }
      if (smode == 0) {
        unsigned kk = (r == 0) ? (unsigned)KDET : sk;
        unsigned acc = 0;
        int bi = nbins - 1;
        for (; bi >= 0; --bi) {
          if (acc + hist[bi] >= kk) break;
          acc += hist[bi];
        }
        sk = kk - acc;   // 1-based position within bin bi
        sprefix = ((r == 0) ? 0u : sprefix) | ((unsigned)bi << shift);
        if (r == 2) { seq = hist[bi]; sabove = KDET - sk; }
      }
    }
    __syncthreads();
    if (smode == 1) break;
  }

  if (smode == 1) {   // total < 300: push every candidate
    for (int n = t; n < NBOX; n += 256) {
      float sc = col[(size_t)n * NCLS];
      if (sc > SCORE_T) {
        unsigned g = atomicAdd(&pushcnt[bc], 1u);
        if (g < CAP) buf[(size_t)bc * CAP + g] = mk_key(sc, n);
      }
    }
    return;
  }

  const unsigned ustar = sprefix;   // exact 300th-largest score bits
  const unsigned m = sabove, e = seq;
  if (m + e <= CAP) {               // push all scores >= s*  (count in [300, CAP])
    for (int n = t; n < NBOX; n += 256) {
      float sc = col[(size_t)n * NCLS];
      if (sc > SCORE_T && __float_as_uint(sc) >= ustar) {
        unsigned g = atomicAdd(&pushcnt[bc], 1u);
        if (g < CAP) buf[(size_t)bc * CAP + g] = mk_key(sc, n);
      }
    }
  } else {                          // heavy ties at s*: strictly-greater in parallel,
    for (int n = t; n < NBOX; n += 256) {   // then lowest-index equals serially
      float sc = col[(size_t)n * NCLS];
      if (sc > SCORE_T && __float_as_uint(sc) > ustar) {
        unsigned g = atomicAdd(&pushcnt[bc], 1u);
        if (g < CAP) buf[(size_t)bc * CAP + g] = mk_key(sc, n);
      }
    }
    __syncthreads();
    if (t == 0) {
      unsigned room = CAP - m, got = 0;
      for (int n = 0; n < NBOX && got < room; ++n) {
        float sc = col[(size_t)n * NCLS];
        if (sc > SCORE_T && __float_as_uint(sc) == ustar) {
          unsigned g = atomicAdd(&pushcnt[bc], 1u);
          if (g < CAP) buf[(size_t)bc * CAP + g] = mk_key(sc, n);
          ++got;
        }
      }
    }
  }
}

// ---------------- per (b,c): exact sort + NMS + compact kept ----------------
__global__ __launch_bounds__(512) void nmsK(const float* __restrict__ boxes,
                                            const unsigned* __restrict__ pushcnt,
                                            const unsigned long long* __restrict__ buf,
                                            unsigned* __restrict__ keptCnt,
                                            float* __restrict__ keptScore,
                                            unsigned* __restrict__ keptIdx) {
  __shared__ unsigned long long sb[CAP];        // 16 KB
  __shared__ float bx[KDET][4];                 // 4.8 KB
  __shared__ float scl[KDET];
  __shared__ unsigned nn[KDET];
  __shared__ unsigned long long msk[KDET][5];   // 12 KB
  __shared__ unsigned long long anyw[5];
  __shared__ unsigned long long keptw[5];

  const int t = threadIdx.x;
  const int bc = blockIdx.x;
  const int b = bc / NCLS;
  const int cnt = min((int)pushcnt[bc], CAP);
  const unsigned long long* src = buf + (size_t)bc * CAP;
  for (int i = t; i < CAP; i += 512) sb[i] = (i < cnt) ? src[i] : 0ull;
  if (t < 5) anyw[t] = 0ull;
  __syncthreads();

  // bitonic sort descending (u64 keys = (score_bits, ~n) -> exact order incl. ties)
  for (int k = 2; k <= CAP; k <<= 1) {
    for (int j = k >> 1; j > 0; j >>= 1) {
      for (int i = t; i < CAP; i += 512) {
        int ixj = i ^ j;
        if (ixj > i) {
          unsigned long long a = sb[i], c2 = sb[ixj];
          bool up = ((i & k) == 0);
          if (up ? (a < c2) : (a > c2)) { sb[i] = c2; sb[ixj] = a; }
        }
      }
      __syncthreads();
    }
  }

  const int M = min(cnt, KDET);
  for (int i = t; i < M; i += 512) {
    unsigned long long key = sb[i];
    unsigned n = ~(unsigned)(key & 0xFFFFFFFFull);
    scl[i] = __uint_as_float((unsigned)(key >> 32));
    nn[i] = n;
    const float4 bv = *(const float4*)(boxes + ((size_t)b * NBOX + n) * 4);
    bx[i][0] = bv.x; bx[i][1] = bv.y; bx[i][2] = bv.z; bx[i][3] = bv.w;
  }
  __syncthreads();

  // suppression masks: bit j of msk[i] set iff IoU(box_i, box_j) >= 0.5, j < i
  for (int i = t; i < M; i += 512) {
    float x1 = bx[i][0], y1 = bx[i][1], x2 = bx[i][2], y2 = bx[i][3];
    float a1 = (x2 - x1) * (y2 - y1);
    unsigned long long m0 = 0, m1 = 0, m2 = 0, m3 = 0, m4 = 0;
    for (int j = 0; j < i; ++j) {
      float lx = fmaxf(x1, bx[j][0]);
      float ly = fmaxf(y1, bx[j][1]);
      float rx = fminf(x2, bx[j][2]);
      float ry = fminf(y2, bx[j][3]);
      float iw = fmaxf(rx - lx, 0.0f), ih = fmaxf(ry - ly, 0.0f);
      float inter = iw * ih;
      float a2 = (bx[j][2] - bx[j][0]) * (bx[j][3] - bx[j][1]);
      float uni = fmaxf(a1 + a2 - inter, 1e-7f);
      float iou = inter / uni;   // true IEEE division: matches reference rounding
      if (iou >= 0.5f) {
        unsigned long long bit = 1ull << (j & 63);
        switch (j >> 6) {
          case 0: m0 |= bit; break;
          case 1: m1 |= bit; break;
          case 2: m2 |= bit; break;
          case 3: m3 |= bit; break;
          default: m4 |= bit; break;
        }
      }
    }
    msk[i][0] = m0; msk[i][1] = m1; msk[i][2] = m2; msk[i][3] = m3; msk[i][4] = m4;
    if (m0 | m1 | m2 | m3 | m4) atomicOr(&anyw[i >> 6], 1ull << (i & 63));
  }
  __syncthreads();

  if (t == 0) {
    unsigned long long kw[5] = {0, 0, 0, 0, 0};
    unsigned long long aw[5] = {anyw[0], anyw[1], anyw[2], anyw[3], anyw[4]};
    for (int i = 0; i < M; ++i) {
      bool sup = false;
      if ((aw[i >> 6] >> (i & 63)) & 1ull) {
        unsigned long long s0 = (msk[i][0] & kw[0]) | (msk[i][1] & kw[1]) |
                                (msk[i][2] & kw[2]) | (msk[i][3] & kw[3]) |
                                (msk[i][4] & kw[4]);
        sup = (s0 != 0ull);
      }
      if (!sup) kw[i >> 6] |= 1ull << (i & 63);
    }
    keptw[0] = kw[0]; keptw[1] = kw[1]; keptw[2] = kw[2]; keptw[3] = kw[3]; keptw[4] = kw[4];
  }
  __syncthreads();

  for (int i = t; i < M; i += 512) {
    if ((keptw[i >> 6] >> (i & 63)) & 1ull) {
      int rank = 0;
      for (int w = 0; w < (i >> 6); ++w) rank += __popcll(keptw[w]);
      rank += __popcll(keptw[i >> 6] & ((1ull << (i & 63)) - 1ull));
      keptScore[(size_t)bc * KDET + rank] = scl[i];
      keptIdx[(size_t)bc * KDET + rank] = nn[i];
    }
  }
  if (t == 0) {
    int tot = 0;
    for (int w = 0; w < 5; ++w) tot += __popcll(keptw[w]);
    keptCnt[bc] = (unsigned)tot;
  }
}

// ---------------- per image: 80-way merge of sorted kept lists ----------------
#define WND 64
__global__ __launch_bounds__(64) void mergeK(const float* __restrict__ boxes,
                                             const unsigned* __restrict__ keptCnt,
                                             const float* __restrict__ keptScore,
                                             const unsigned* __restrict__ keptIdx,
                                             float* __restrict__ out) {
  __shared__ float win[NCLS][WND + 1];
  __shared__ int scnt[NCLS];
  __shared__ unsigned long long wkey[KDET];
  __shared__ int wptr[KDET];

  const int lane = threadIdx.x;
  const int b = blockIdx.x;

  for (int c = lane; c < NCLS; c += 64) scnt[c] = min((int)keptCnt[b * NCLS + c], KDET);
  __syncthreads();
  for (int idx = lane; idx < NCLS * WND; idx += 64) {
    int c = idx >> 6, i = idx & 63;
    if (i < scnt[c]) win[c][i] = keptScore[((size_t)b * NCLS + c) * KDET + i];
  }
  __syncthreads();

  const int cnt0 = scnt[lane];
  const int cnt1 = (lane < 16) ? scnt[64 + lane] : 0;
  int p0 = 0, p1 = 0;

  for (int step = 0; step < KDET; ++step) {
    unsigned long long k0 = 0, k1 = 0;
    if (p0 < cnt0) {
      float s = (p0 < WND) ? win[lane][p0]
                           : keptScore[((size_t)b * NCLS + lane) * KDET + p0];
      k0 = ((unsigned long long)__float_as_uint(s) << 32) | (unsigned)(~(unsigned)lane);
    }
    if (lane < 16 && p1 < cnt1) {
      int c = 64 + lane;
      float s = (p1 < WND) ? win[c][p1]
                           : keptScore[((size_t)b * NCLS + c) * KDET + p1];
      k1 = ((unsigned long long)__float_as_uint(s) << 32) | (unsigned)(~(unsigned)c);
    }
    unsigned long long key = (k0 > k1) ? k0 : k1;
#pragma unroll
    for (int off = 32; off > 0; off >>= 1) {
      unsigned long long o = __shfl_xor(key, off);
      if (o > key) key = o;
    }
    if (key == 0ull) {
      if (lane == 0) wkey[step] = 0ull;
    } else {
      unsigned c = ~(unsigned)(key & 0xFFFFFFFFull);
      int wl = (int)(c & 63);
      if (lane == wl) {
        if ((int)c == lane) { wptr[step] = p0; ++p0; }
        else               { wptr[step] = p1; ++p1; }
        wkey[step] = key;
      }
    }
  }
  __syncthreads();

  float* ob_base = out;
  float* os_base = out + (size_t)BIMG * KDET * 4;
  float* ol_base = out + (size_t)BIMG * KDET * 4 + (size_t)BIMG * KDET;
  for (int w = lane; w < KDET; w += 64) {
    unsigned long long key = wkey[w];
    float* ob = ob_base + ((size_t)b * KDET + w) * 4;
    if (key == 0ull) {
      *(float4*)ob = make_float4(-1.f, -1.f, -1.f, -1.f);
      os_base[(size_t)b * KDET + w] = -1.f;
      ol_base[(size_t)b * KDET + w] = -1.f;
    } else {
      unsigned c = ~(unsigned)(key & 0xFFFFFFFFull);
      float sc = __uint_as_float((unsigned)(key >> 32));
      unsigned n = keptIdx[((size_t)b * NCLS + c) * KDET + wptr[w]];
      *(float4*)ob = *(const float4*)(boxes + ((size_t)b * NBOX + n) * 4);
      os_base[(size_t)b * KDET + w] = sc;
      ol_base[(size_t)b * KDET + w] = (float)c;
    }
  }
}

extern "C" void kernel_launch(void* const* d_in, const int* in_sizes, int n_in,
                              void* d_out, int out_size, void* d_ws, size_t ws_size,
                              hipStream_t stream) {
  const float* boxes = (const float*)d_in[0];
  const float* cls = (const float*)d_in[1];
  float* out = (float*)d_out;
  char* ws = (char*)d_ws;

  unsigned* pushcnt = (unsigned*)(ws + OFF_PUSHCNT);
  unsigned long long* buf = (unsigned long long*)(ws + OFF_BUF);
  unsigned* keptCnt = (unsigned*)(ws + OFF_KCNT);
  float* keptScore = (float*)(ws + OFF_KSC);
  unsigned* keptIdx = (unsigned*)(ws + OFF_KIDX);

  hipMemsetAsync(ws + OFF_PUSHCNT, 0, ZERO_BYTES, stream);

  histK<<<dim3(246, BIMG), 256, 0, stream>>>(cls, pushcnt, buf);
  fbK<<<BIMG * NCLS, 256, 0, stream>>>(cls, pushcnt, buf);
  nmsK<<<BIMG * NCLS, 512, 0, stream>>>(boxes, pushcnt, buf, keptCnt, keptScore, keptIdx);
  mergeK<<<BIMG, 64, 0, stream>>>(boxes, keptCnt, keptScore, keptIdx, out);
}

// Round 4
// 525.993 us; speedup vs baseline: 2.0529x; 1.3133x over previous
//
#include <hip/hip_runtime.h>

#define BIMG 8
#define NBOX 100000
#define NCLS 80
#define KDET 300
#define CAP  2048
#define CAPC 20                 // per-block per-class LDS staging capacity
#define TPUSH 0.984375f         // common-path push threshold (126/128)
#define SCORE_T 0.05f
#define NELEM 8000000           // N*C per image
#define NQ    2000000           // float4s per image

typedef unsigned long long u64;
typedef unsigned u32;

// workspace layout (bytes)
#define OFF_PUSHCNT 0u              // 640*4 = 2560
#define ZERO_BYTES  2560u
#define OFF_BUF     4096u           // 640*2048*8 = 10485760
#define OFF_KCNT    (4096u + 10485760u)     // 640*4
#define OFF_KSC     (OFF_KCNT + 2560u)      // 640*300*4
#define OFF_KIDX    (OFF_KSC + 768000u)     // 640*300*4

static __device__ __forceinline__ u64 mk_key(float sc, u32 n) {
  return ((u64)__float_as_uint(sc) << 32) | (u32)(~n);
}

// One radix-select step over `hist[nbins]` (single copy), executed by wave 0.
// Finds bin of the sk-th largest (counting from top), updates spfx/sk.
// Caller must __syncthreads() before and after. Writes total into *stot (lane0).
static __device__ __forceinline__ void radix_step(const u32* hist, int nbins,
                                                  int width, u32* sk, u64* spfx,
                                                  u32* stot) {
  if (threadIdx.x < 64) {
    const int lane = threadIdx.x;
    const int chunk = nbins >> 6;
    u32 psum = 0;
    for (int i = 0; i < chunk; ++i) psum += hist[lane * chunk + i];
    u32 suf = psum;
#pragma unroll
    for (int off = 1; off < 64; off <<= 1) {
      u32 o = __shfl_down(suf, off);
      if (lane + off < 64) suf += o;
    }
    if (lane == 0) *stot = suf;          // lane0 suffix == total
    u32 k = *sk;
    u64 bal = __ballot(suf >= k);
    if (bal != 0ull) {
      int L = 63 - __clzll((long long)bal);
      if (lane == L) {
        u32 krem = k - (suf - psum);     // remaining within this chunk (from top)
        int bi = (L + 1) * chunk - 1;
        u32 acc = 0;
        for (;;) {
          acc += hist[bi];
          if (acc >= krem || bi == L * chunk) break;
          --bi;
        }
        *spfx = (*spfx << width) | (u32)bi;
        *sk = krem - (acc - hist[bi]);
      }
    }
  }
}

__constant__ int RSH[6] = {53, 42, 31, 20, 9, 0};
__constant__ int RWD[6] = {11, 11, 11, 11, 11, 9};

// ---------------- pass A: threshold push with block-local aggregation ----------------
static __device__ __forceinline__ void pushone(int c, float sc, u32 n, int b,
                                               u32* lcnt, u64* stage,
                                               u32* pushcnt, u64* buf) {
  u64 key = mk_key(sc, n);
  u32 slot = atomicAdd(&lcnt[c], 1u);
  if (slot < CAPC) {
    stage[c * CAPC + slot] = key;
  } else {    // rare LDS-staging overflow: direct global push
    u32 g = atomicAdd(&pushcnt[b * NCLS + c], 1u);
    if (g < CAP) buf[(size_t)(b * NCLS + c) * CAP + g] = key;
  }
}

__global__ __launch_bounds__(256) void histK(const float* __restrict__ cls,
                                             u32* __restrict__ pushcnt,
                                             u64* __restrict__ buf) {
  __shared__ u32 lcnt[NCLS];
  __shared__ u32 sbase[NCLS];
  __shared__ u64 stage[NCLS * CAPC];   // 12.8 KB

  const int t = threadIdx.x;
  const int b = blockIdx.y;
  for (int i = t; i < NCLS; i += 256) lcnt[i] = 0;
  __syncthreads();

  const float4* base4 = (const float4*)(cls + (size_t)b * NELEM);
  const int start = blockIdx.x * 8192;   // 246 blocks/img * 8192 float4 >= 2M

#define LOADQ(u) const int q##u = qb + (u) * 256; \
  const float4 v##u = (q##u < NQ) ? base4[q##u] : make_float4(0.f, 0.f, 0.f, 0.f)
#define PROCQ(u) do { \
    float mx = fmaxf(fmaxf(v##u.x, v##u.y), fmaxf(v##u.z, v##u.w)); \
    if (mx >= TPUSH) { \
      const int e0 = q##u * 4; \
      const int c0 = e0 % NCLS; \
      const u32 n = (u32)(e0 / NCLS); \
      if (v##u.x >= TPUSH) pushone(c0 + 0, v##u.x, n, b, lcnt, stage, pushcnt, buf); \
      if (v##u.y >= TPUSH) pushone(c0 + 1, v##u.y, n, b, lcnt, stage, pushcnt, buf); \
      if (v##u.z >= TPUSH) pushone(c0 + 2, v##u.z, n, b, lcnt, stage, pushcnt, buf); \
      if (v##u.w >= TPUSH) pushone(c0 + 3, v##u.w, n, b, lcnt, stage, pushcnt, buf); \
    } } while (0)

  for (int it = 0; it < 4; ++it) {
    const int qb = start + it * 2048 + t;
    LOADQ(0); LOADQ(1); LOADQ(2); LOADQ(3);
    LOADQ(4); LOADQ(5); LOADQ(6); LOADQ(7);
    PROCQ(0); PROCQ(1); PROCQ(2); PROCQ(3);
    PROCQ(4); PROCQ(5); PROCQ(6); PROCQ(7);
  }
#undef LOADQ
#undef PROCQ
  __syncthreads();

  // one global atomic per (block, class) to reserve a contiguous range
  if (t < NCLS) {
    u32 cnt = min(lcnt[t], (u32)CAPC);
    sbase[t] = cnt ? atomicAdd(&pushcnt[b * NCLS + t], cnt) : 0u;
  }
  __syncthreads();
  for (int idx = t; idx < NCLS * CAPC; idx += 256) {
    const int c = idx / CAPC;
    const int k = idx - c * CAPC;
    if ((u32)k < min(lcnt[c], (u32)CAPC)) {
      u32 s = sbase[c] + (u32)k;
      if (s < CAP) buf[(size_t)(b * NCLS + c) * CAP + s] = stage[idx];
    }
  }
}

// ---------------- fallback: exact radix-select re-push (early-exits; never runs on
// common inputs). One block per (b,c). ----------------
__global__ __launch_bounds__(256) void fbK(const float* __restrict__ cls,
                                           u32* __restrict__ pushcnt,
                                           u64* __restrict__ buf) {
  const int bc = blockIdx.x;
  const u32 cnt = pushcnt[bc];
  if (cnt >= KDET && cnt <= CAP) return;   // common path: superset covers top-300

  __shared__ u32 hist[2048];               // 8 KB
  __shared__ u32 sprefix, sk, sabove, seq, stot, smode;

  const int t = threadIdx.x;
  const int b = bc / NCLS, c = bc % NCLS;
  const float* col = cls + (size_t)b * NELEM + c;
  if (t == 0) { atomicExch(&pushcnt[bc], 0u); smode = 0; }

  // MSD radix-select of the 300th-largest score-bits (positive floats: bits monotone)
  for (int r = 0; r < 3; ++r) {
    const int shift = (r == 0) ? 21 : (r == 1) ? 10 : 0;
    const int nbins = (r == 2) ? 1024 : 2048;
    for (int i = t; i < nbins; i += 256) hist[i] = 0;
    __syncthreads();
    for (int n = t; n < NBOX; n += 256) {
      float sc = col[(size_t)n * NCLS];
      if (sc > SCORE_T) {
        u32 u = __float_as_uint(sc);
        bool ok = (r == 0) || (r == 1 ? ((u >> 21) == (sprefix >> 21))
                                      : ((u >> 10) == (sprefix >> 10)));
        if (ok) atomicAdd(&hist[(u >> shift) & (u32)(nbins - 1)], 1u);
      }
    }
    __syncthreads();
    if (t == 0) {
      if (r == 0) {
        u32 s = 0;
        for (int i = 0; i < nbins; ++i) s += hist[i];
        stot = s;
        if (s < KDET) smode = 1;   // fewer than 300 candidates: push all
      }
      if (smode == 0) {
        u32 kk = (r == 0) ? (u32)KDET : sk;
        u32 acc = 0;
        int bi = nbins - 1;
        for (; bi >= 0; --bi) {
          if (acc + hist[bi] >= kk) break;
          acc += hist[bi];
        }
        sk = kk - acc;
        sprefix = ((r == 0) ? 0u : sprefix) | ((u32)bi << shift);
        if (r == 2) { seq = hist[bi]; sabove = KDET - sk; }
      }
    }
    __syncthreads();
    if (smode == 1) break;
  }

  if (smode == 1) {
    for (int n = t; n < NBOX; n += 256) {
      float sc = col[(size_t)n * NCLS];
      if (sc > SCORE_T) {
        u32 g = atomicAdd(&pushcnt[bc], 1u);
        if (g < CAP) buf[(size_t)bc * CAP + g] = mk_key(sc, (u32)n);
      }
    }
    return;
  }

  const u32 ustar = sprefix;
  const u32 m = sabove, e = seq;
  if (m + e <= CAP) {
    for (int n = t; n < NBOX; n += 256) {
      float sc = col[(size_t)n * NCLS];
      if (sc > SCORE_T && __float_as_uint(sc) >= ustar) {
        u32 g = atomicAdd(&pushcnt[bc], 1u);
        if (g < CAP) buf[(size_t)bc * CAP + g] = mk_key(sc, (u32)n);
      }
    }
  } else {
    for (int n = t; n < NBOX; n += 256) {
      float sc = col[(size_t)n * NCLS];
      if (sc > SCORE_T && __float_as_uint(sc) > ustar) {
        u32 g = atomicAdd(&pushcnt[bc], 1u);
        if (g < CAP) buf[(size_t)bc * CAP + g] = mk_key(sc, (u32)n);
      }
    }
    __syncthreads();
    if (t == 0) {
      u32 room = CAP - m, got = 0;
      for (int n = 0; n < NBOX && got < room; ++n) {
        float sc = col[(size_t)n * NCLS];
        if (sc > SCORE_T && __float_as_uint(sc) == ustar) {
          u32 g = atomicAdd(&pushcnt[bc], 1u);
          if (g < CAP) buf[(size_t)bc * CAP + g] = mk_key(sc, (u32)n);
          ++got;
        }
      }
    }
  }
}

// ---------------- per (b,c): radix top-300 + sort-512 + NMS + compact ----------------
__global__ __launch_bounds__(512) void nmsK(const float* __restrict__ boxes,
                                            const u32* __restrict__ pushcnt,
                                            const u64* __restrict__ buf,
                                            u32* __restrict__ keptCnt,
                                            float* __restrict__ keptScore,
                                            u32* __restrict__ keptIdx) {
  __shared__ float bx[KDET][4];                 // 4.8 KB
  __shared__ float scl[KDET];
  __shared__ u32 nn_[KDET];
  __shared__ u64 msk[KDET][5];                  // 12 KB (aliased as hist early)
  __shared__ u64 tk[512];                       // 4 KB
  __shared__ u64 anyw[5];
  __shared__ u64 keptw[5];
  __shared__ u64 spfx;
  __shared__ u32 sk, stot, stcnt;

  const int t = threadIdx.x;
  const int bc = blockIdx.x;
  const int b = bc / NCLS;
  const int cnt = min((int)pushcnt[bc], CAP);
  const u64* src = buf + (size_t)bc * CAP;

  u64 kk[4];
#pragma unroll
  for (int u = 0; u < 4; ++u) {
    int i = t + u * 512;
    kk[u] = (i < cnt) ? src[i] : 0ull;
  }
  if (t == 0) { spfx = 0ull; sk = KDET; stcnt = 0u; }
  if (t < 5) anyw[t] = 0ull;
  u32* hist = (u32*)&msk[0][0];   // 2048-bin scratch, dead before masks are built

  const bool normal = (cnt > KDET);   // block-uniform
  if (normal) {
    for (int p = 0; p < 6; ++p) {
      const int nb = (p == 5) ? 512 : 2048;
      for (int i = t; i < nb; i += 512) hist[i] = 0;
      __syncthreads();
      const u64 pfx = spfx;
#pragma unroll
      for (int u = 0; u < 4; ++u) {
        u64 key = kk[u];
        if (!key) continue;
        if (p > 0 && (key >> RSH[p - 1]) != pfx) continue;
        atomicAdd(&hist[(u32)(key >> RSH[p]) & (u32)(nb - 1)], 1u);
      }
      __syncthreads();
      radix_step(hist, nb, RWD[p], &sk, &spfx, &stot);
      __syncthreads();
    }
  } else {
    __syncthreads();
  }
  const u64 thr = normal ? spfx : 1ull;   // exact 300th-largest key (keys unique)

  tk[t] = 0ull;
  __syncthreads();
#pragma unroll
  for (int u = 0; u < 4; ++u) {
    u64 key = kk[u];
    if (key >= thr && key != 0ull) {
      u32 pos = atomicAdd(&stcnt, 1u);
      if (pos < 512) tk[pos] = key;
    }
  }
  __syncthreads();

  // bitonic sort 512 descending (exact order: unique u64 keys)
  for (int k2 = 2; k2 <= 512; k2 <<= 1) {
    for (int j = k2 >> 1; j > 0; j >>= 1) {
      int i = t, ixj = i ^ j;
      if (ixj > i) {
        u64 a = tk[i], c2 = tk[ixj];
        bool up = ((i & k2) == 0);
        if (up ? (a < c2) : (a > c2)) { tk[i] = c2; tk[ixj] = a; }
      }
      __syncthreads();
    }
  }

  const int M = min((int)stcnt, KDET);
  for (int i = t; i < M; i += 512) {
    u64 key = tk[i];
    u32 n = ~(u32)key;
    scl[i] = __uint_as_float((u32)(key >> 32));
    nn_[i] = n;
    const float4 bv = *(const float4*)(boxes + ((size_t)b * NBOX + n) * 4);
    bx[i][0] = bv.x; bx[i][1] = bv.y; bx[i][2] = bv.z; bx[i][3] = bv.w;
  }
  __syncthreads();

  // suppression masks: bit j of msk[i] set iff IoU(box_i, box_j) >= 0.5, j < i
  for (int i = t; i < M; i += 512) {
    float x1 = bx[i][0], y1 = bx[i][1], x2 = bx[i][2], y2 = bx[i][3];
    float a1 = (x2 - x1) * (y2 - y1);
    u64 m0 = 0, m1 = 0, m2 = 0, m3 = 0, m4 = 0;
    for (int j = 0; j < i; ++j) {
      float lx = fmaxf(x1, bx[j][0]);
      float ly = fmaxf(y1, bx[j][1]);
      float rx = fminf(x2, bx[j][2]);
      float ry = fminf(y2, bx[j][3]);
      float iw = fmaxf(rx - lx, 0.0f), ih = fmaxf(ry - ly, 0.0f);
      float inter = iw * ih;
      float a2 = (bx[j][2] - bx[j][0]) * (bx[j][3] - bx[j][1]);
      float uni = fmaxf(a1 + a2 - inter, 1e-7f);
      float iou = inter / uni;   // true IEEE division: matches reference rounding
      if (iou >= 0.5f) {
        u64 bit = 1ull << (j & 63);
        switch (j >> 6) {
          case 0: m0 |= bit; break;
          case 1: m1 |= bit; break;
          case 2: m2 |= bit; break;
          case 3: m3 |= bit; break;
          default: m4 |= bit; break;
        }
      }
    }
    msk[i][0] = m0; msk[i][1] = m1; msk[i][2] = m2; msk[i][3] = m3; msk[i][4] = m4;
    if (m0 | m1 | m2 | m3 | m4) atomicOr(&anyw[i >> 6], 1ull << (i & 63));
  }
  __syncthreads();

  if (t == 0) {
    u64 kw[5] = {0, 0, 0, 0, 0};
    u64 aw[5] = {anyw[0], anyw[1], anyw[2], anyw[3], anyw[4]};
    for (int i = 0; i < M; ++i) {
      bool sup = false;
      if ((aw[i >> 6] >> (i & 63)) & 1ull) {
        u64 s0 = (msk[i][0] & kw[0]) | (msk[i][1] & kw[1]) |
                 (msk[i][2] & kw[2]) | (msk[i][3] & kw[3]) |
                 (msk[i][4] & kw[4]);
        sup = (s0 != 0ull);
      }
      if (!sup) kw[i >> 6] |= 1ull << (i & 63);
    }
    keptw[0] = kw[0]; keptw[1] = kw[1]; keptw[2] = kw[2];
    keptw[3] = kw[3]; keptw[4] = kw[4];
  }
  __syncthreads();

  for (int i = t; i < M; i += 512) {
    if ((keptw[i >> 6] >> (i & 63)) & 1ull) {
      int rank = 0;
      for (int w = 0; w < (i >> 6); ++w) rank += __popcll(keptw[w]);
      rank += __popcll(keptw[i >> 6] & ((1ull << (i & 63)) - 1ull));
      keptScore[(size_t)bc * KDET + rank] = scl[i];
      keptIdx[(size_t)bc * KDET + rank] = nn_[i];
    }
  }
  if (t == 0) {
    int tot = 0;
    for (int w = 0; w < 5; ++w) tot += __popcll(keptw[w]);
    keptCnt[bc] = (u32)tot;
  }
}

// ---------------- per image: parallel radix top-300 across all classes ----------------
#define MSLOT 24   // ceil(80*300/1024)
__global__ __launch_bounds__(1024) void mergeK(const float* __restrict__ boxes,
                                               const u32* __restrict__ keptCnt,
                                               const float* __restrict__ keptScore,
                                               const u32* __restrict__ keptIdx,
                                               float* __restrict__ out) {
  __shared__ u32 hist[4 * 2048];   // 32 KB, 4 privatized copies
  __shared__ int scnt[NCLS];
  __shared__ u64 tk[512];
  __shared__ u64 spfx, sthr;
  __shared__ u32 sk, stot, smode, stcnt;

  const int t = threadIdx.x;
  const int b = blockIdx.x;
  if (t < NCLS) scnt[t] = min((int)keptCnt[b * NCLS + t], KDET);
  if (t == 0) { spfx = 0ull; sk = KDET; smode = 0u; stcnt = 0u; }
  __syncthreads();

  // keys (score_bits<<32)|~(c*KDET+r) in registers; 0 = invalid
  u64 kk[MSLOT];
  const float* ksc = keptScore + (size_t)b * NCLS * KDET;
#pragma unroll
  for (int u = 0; u < MSLOT; ++u) {
    int idx = t + u * 1024;
    u64 key = 0ull;
    if (idx < NCLS * KDET) {
      int c = idx / KDET, r = idx - c * KDET;
      if (r < scnt[c])
        key = ((u64)__float_as_uint(ksc[idx]) << 32) | (u32)(~(u32)idx);
    }
    kk[u] = key;
  }

  for (int p = 0; p < 6; ++p) {
    const int nb = (p == 5) ? 512 : 2048;
    for (int i = t; i < 4 * 2048; i += 1024) hist[i] = 0;
    __syncthreads();
    u32* hp = hist + ((t >> 8) & 3) * 2048;
    const u64 pfx = spfx;
#pragma unroll
    for (int u = 0; u < MSLOT; ++u) {
      u64 key = kk[u];
      if (!key) continue;
      if (p > 0 && (key >> RSH[p - 1]) != pfx) continue;
      atomicAdd(&hp[(u32)(key >> RSH[p]) & (u32)(nb - 1)], 1u);
    }
    __syncthreads();
    for (int i = t; i < nb; i += 1024)
      hist[i] = hist[i] + hist[2048 + i] + hist[4096 + i] + hist[6144 + i];
    __syncthreads();
    radix_step(hist, nb, RWD[p], &sk, &spfx, &stot);
    __syncthreads();
    if (p == 0) {
      if (t == 0 && stot <= KDET) smode = 1u;
      __syncthreads();
      if (smode) break;
    }
  }
  if (t == 0) sthr = smode ? 1ull : spfx;
  if (t < 512) tk[t] = 0ull;
  __syncthreads();

  const u64 thr = sthr;
#pragma unroll
  for (int u = 0; u < MSLOT; ++u) {
    u64 key = kk[u];
    if (key >= thr && key != 0ull) {
      u32 pos = atomicAdd(&stcnt, 1u);
      if (pos < 512) tk[pos] = key;
    }
  }
  __syncthreads();

  // bitonic sort 512 descending
  for (int k2 = 2; k2 <= 512; k2 <<= 1) {
    for (int j = k2 >> 1; j > 0; j >>= 1) {
      if (t < 512) {
        int i = t, ixj = i ^ j;
        if (ixj > i) {
          u64 a = tk[i], c2 = tk[ixj];
          bool up = ((i & k2) == 0);
          if (up ? (a < c2) : (a > c2)) { tk[i] = c2; tk[ixj] = a; }
        }
      }
      __syncthreads();
    }
  }

  // outputs: boxes [B,K,4] | scores [B,K] | labels [B,K] (as float)
  if (t < KDET) {
    float* ob = out + ((size_t)b * KDET + t) * 4;
    float* os = out + (size_t)BIMG * KDET * 4;
    float* ol = os + (size_t)BIMG * KDET;
    u64 key = tk[t];
    if (key == 0ull) {
      *(float4*)ob = make_float4(-1.f, -1.f, -1.f, -1.f);
      os[(size_t)b * KDET + t] = -1.f;
      ol[(size_t)b * KDET + t] = -1.f;
    } else {
      u32 fi = ~(u32)key;
      int c = fi / KDET, r = fi - c * KDET;
      u32 n = keptIdx[((size_t)b * NCLS + c) * KDET + r];
      *(float4*)ob = *(const float4*)(boxes + ((size_t)b * NBOX + n) * 4);
      os[(size_t)b * KDET + t] = __uint_as_float((u32)(key >> 32));
      ol[(size_t)b * KDET + t] = (float)c;
    }
  }
}

extern "C" void kernel_launch(void* const* d_in, const int* in_sizes, int n_in,
                              void* d_out, int out_size, void* d_ws, size_t ws_size,
                              hipStream_t stream) {
  const float* boxes = (const float*)d_in[0];
  const float* cls = (const float*)d_in[1];
  float* out = (float*)d_out;
  char* ws = (char*)d_ws;

  u32* pushcnt = (u32*)(ws + OFF_PUSHCNT);
  u64* buf = (u64*)(ws + OFF_BUF);
  u32* keptCnt = (u32*)(ws + OFF_KCNT);
  float* keptScore = (float*)(ws + OFF_KSC);
  u32* keptIdx = (u32*)(ws + OFF_KIDX);

  (void)hipMemsetAsync(ws + OFF_PUSHCNT, 0, ZERO_BYTES, stream);

  histK<<<dim3(246, BIMG), 256, 0, stream>>>(cls, pushcnt, buf);
  fbK<<<BIMG * NCLS, 256, 0, stream>>>(cls, pushcnt, buf);
  nmsK<<<BIMG * NCLS, 512, 0, stream>>>(boxes, pushcnt, buf, keptCnt, keptScore, keptIdx);
  mergeK<<<BIMG, 1024, 0, stream>>>(boxes, keptCnt, keptScore, keptIdx, out);
}